// Round 12
// baseline (119.455 us; speedup 1.0000x reference)
//
#include <hip/hip_runtime.h>
#include <hip/hip_bf16.h>

#define NB   8192   // batch
#define NS   10     // neighbor seq len
#define NT   3      // node types
#define NN   65536  // table size
#define ND   128    // embed dim
#define NL   2      // layers
#define ROWS 16     // batch rows per block

typedef __attribute__((ext_vector_type(8))) short bf16x8;
typedef __attribute__((ext_vector_type(4))) float f32x4;

__device__ __forceinline__ unsigned int pk2(float lo, float hi) {
    unsigned int r;
    asm("v_cvt_pk_bf16_f32 %0, %1, %2" : "=v"(r) : "v"(lo), "v"(hi));
    return r;
}
// tanh(x) = 1 - 2/(exp2(2*log2e*x)+1)
__device__ __forceinline__ float tanh_f(float x) {
    float e, r;
    asm("v_exp_f32 %0, %1" : "=v"(e) : "v"(x * 2.88539004f));
    asm("v_rcp_f32 %0, %1" : "=v"(r) : "v"(e + 1.0f));
    return fmaf(-2.0f, r, 1.0f);
}
// Barrier with LDS-only drain: global (vmcnt) loads stay in flight across it.
__device__ __forceinline__ void bar_lgkm() {
    asm volatile("s_waitcnt lgkmcnt(0)\n\ts_barrier" ::: "memory");
}

// ---------------------------------------------------------------------------
// RNN kernel: grid = NT*512 blocks, 256 threads (4 waves = layer(2) x e-half(2)).
// Block owns (t, 16 batch rows), both layers; wave computes a 64-e slice.
// r12 change vs r11: ALL 8 B-fragments (X + H) preloaded into registers
// BEFORE the MFMA block -> one batched LDS latency per step instead of eight
// exposed ~120cy read->MFMA stalls (r11 post-mortem: 8x120cy/step matched the
// 124us wall at 1 wave/SIMD). W2=[Wih;Whh] 64-e slice in regs; NO min-waves
// launch_bounds arg (r7/r10: cap below working set = scratch spills).
// X staged once/step for both layers; X and per-layer H double-buffered in
// LDS ([16][128] bf16, XOR-swizzled 16B chunks); ONE lgkm-only barrier per
// step; register gather prefetch in flight across it (vmcnt undrained).
// ---------------------------------------------------------------------------
__global__ __launch_bounds__(256)
void rnn_kernel(const float* __restrict__ emb, const float* __restrict__ Wih,
                const float* __restrict__ Whh, const float* __restrict__ bih,
                const float* __restrict__ bhh, const int* __restrict__ nidx,
                float* __restrict__ agg)
{
    // [X p0 | X p1 | H(l0) p0 | H(l0) p1 | H(l1) p0 | H(l1) p1], 4 KB each
    __shared__ __align__(16) char lds[6 * 4096];

    const int bid = blockIdx.x;                 // NT * (NB/ROWS)
    const int t   = bid / (NB / ROWS);
    const int b0  = (bid % (NB / ROWS)) * ROWS;

    const int tid  = threadIdx.x;
    const int wv   = tid >> 6;
    const int lay  = wv >> 1;        // layer 0/1
    const int lane = tid & 63;
    const int l16  = lane & 15;
    const int lg   = lane >> 4;
    const int e0   = (wv & 1) * 64;  // e-half within layer
    const int rx   = l16 & 7;        // read-swizzle key

    char* xb = lds;
    char* hb = lds + 8192 + lay * 8192;

    // staging geometry: 16 threads per row, 8 floats (one 16B bf16 chunk) each
    const int srow  = tid >> 4;      // 0..15
    const int sq    = tid & 15;      // chunk index
    const int xaddr = srow * 256 + ((sq ^ (srow & 7)) << 4);

    // ---- preload all neighbor indices for this row ----
    const int* ip = nidx + ((size_t)t * NB + b0 + srow) * NS;
    int idxs[NS];
    #pragma unroll
    for (int s = 0; s < NS; ++s) idxs[s] = ip[s];

    // ---- prefetch s=0 gather (lands while W-fragments are built) ----
    float4 P0, P1;
    {
        const float* src = emb + ((size_t)t * NN + idxs[0]) * ND + sq * 8;
        P0 = *(const float4*)(src);
        P1 = *(const float4*)(src + 4);
    }

    const float* Wih_lt = Wih + (size_t)(lay * NT + t) * ND * ND;
    const float* Whh_lt = Whh + (size_t)(lay * NT + t) * ND * ND;
    const float* bih_lt = bih + (size_t)(lay * NT + t) * ND;
    const float* bhh_lt = bhh + (size_t)(lay * NT + t) * ND;

    // ---- A-fragments: rows e = e0 + mt*16 + l16, k-chunk kc (kc<4: Wih) ----
    bf16x8 Af[4][8];
    #pragma unroll
    for (int mt = 0; mt < 4; ++mt) {
        #pragma unroll
        for (int kc = 0; kc < 8; ++kc) {
            const float* Wsrc = (kc < 4) ? Wih_lt : Whh_lt;
            const float* srcp = Wsrc + (size_t)(e0 + mt * 16 + l16) * ND + (kc & 3) * 32 + lg * 8;
            float4 p0 = *(const float4*)(srcp);
            float4 p1 = *(const float4*)(srcp + 4);
            int4 a;
            a.x = (int)pk2(p0.x, p0.y);
            a.y = (int)pk2(p0.z, p0.w);
            a.z = (int)pk2(p1.x, p1.y);
            a.w = (int)pk2(p1.z, p1.w);
            Af[mt][kc] = *(bf16x8*)&a;
        }
    }

    // bias folded into MFMA C-init
    f32x4 biasv[4];
    #pragma unroll
    for (int mt = 0; mt < 4; ++mt) {
        int e = e0 + mt * 16 + lg * 4;
        float4 bi = *(const float4*)(bih_lt + e);
        float4 bh = *(const float4*)(bhh_lt + e);
        biasv[mt][0] = bi.x + bh.x;
        biasv[mt][1] = bi.y + bh.y;
        biasv[mt][2] = bi.z + bh.z;
        biasv[mt][3] = bi.w + bh.w;
    }

    // precomputed swizzled LDS addresses
    int raddr[4];      // B-frag reads (X and H share the [16][128] pattern)
    #pragma unroll
    for (int c = 0; c < 4; ++c)
        raddr[c] = l16 * 256 + (((c * 4 + lg) ^ rx) << 4);
    int hwaddr[4];     // packed H writes: es = e0 + mt*16 + lg*4
    #pragma unroll
    for (int mt = 0; mt < 4; ++mt) {
        int es = e0 + mt * 16 + lg * 4;
        hwaddr[mt] = l16 * 256 + (((es >> 3) ^ rx) << 4) + (es & 7) * 2;
    }

    f32x4 zero4; zero4[0] = 0.f; zero4[1] = 0.f; zero4[2] = 0.f; zero4[3] = 0.f;
    f32x4 Ag[4];
    #pragma unroll
    for (int mt = 0; mt < 4; ++mt) Ag[mt] = zero4;

    #pragma unroll
    for (int s = 0; s < NS; ++s) {
        // ---- pack prefetched X_s -> swizzled LDS store (1x ds_write_b128) ----
        {
            int4 pk;
            pk.x = (int)pk2(P0.x, P0.y);
            pk.y = (int)pk2(P0.z, P0.w);
            pk.z = (int)pk2(P1.x, P1.y);
            pk.w = (int)pk2(P1.z, P1.w);
            *(int4*)(xb + xaddr + (s & 1) * 4096) = pk;
        }
        // ---- issue next-step gather; stays in flight across the barrier ----
        if (s + 1 < NS) {
            const float* src = emb + ((size_t)t * NN + idxs[s + 1]) * ND + sq * 8;
            P0 = *(const float4*)(src);
            P1 = *(const float4*)(src + 4);
        }
        bar_lgkm();   // X_s and H_{s-1} visible to all 4 waves; vmcnt in flight

        // ---- batch-load ALL B-fragments first (one LDS latency, not eight) ----
        bf16x8 bfr[8];
        #pragma unroll
        for (int c = 0; c < 4; ++c)
            bfr[c] = *(const bf16x8*)(xb + raddr[c] + (s & 1) * 4096);
        if (s > 0) {
            #pragma unroll
            for (int c = 0; c < 4; ++c)
                bfr[4 + c] = *(const bf16x8*)(hb + raddr[c] + ((s + 1) & 1) * 4096);
        }

        // ---- acc = bias + W2-slice x Z-rows (K=256: X then H of own layer) ----
        f32x4 acc[4];
        #pragma unroll
        for (int mt = 0; mt < 4; ++mt) acc[mt] = biasv[mt];

        #pragma unroll
        for (int c = 0; c < 4; ++c)
            #pragma unroll
            for (int mt = 0; mt < 4; ++mt)
                acc[mt] = __builtin_amdgcn_mfma_f32_16x16x32_bf16(Af[mt][c], bfr[c], acc[mt], 0, 0, 0);
        if (s > 0) {
            #pragma unroll
            for (int c = 0; c < 4; ++c)
                #pragma unroll
                for (int mt = 0; mt < 4; ++mt)
                    acc[mt] = __builtin_amdgcn_mfma_f32_16x16x32_bf16(Af[mt][c + 4], bfr[4 + c], acc[mt], 0, 0, 0);
        }

        // ---- tanh + agg accumulate + packed H writeback (other H buffer) ----
        #pragma unroll
        for (int mt = 0; mt < 4; ++mt) {
            f32x4 h;
            #pragma unroll
            for (int i = 0; i < 4; ++i)
                h[i] = tanh_f(acc[mt][i]);
            Ag[mt] += h;
            int2 pk;
            pk.x = (int)pk2(h[0], h[1]);
            pk.y = (int)pk2(h[2], h[3]);
            *(int2*)(hb + hwaddr[mt] + (s & 1) * 4096) = pk;
        }
    }

    // agg[l][t][b][e]: lane writes float4 of 4 consecutive e at its row b
    float* aggp = agg + ((size_t)(lay * NT + t) * NB + b0) * ND;
    #pragma unroll
    for (int mt = 0; mt < 4; ++mt) {
        f32x4 v = Ag[mt] * 0.1f;
        *(f32x4*)(aggp + (size_t)l16 * ND + e0 + mt * 16 + lg * 4) = v;
    }
}

// ---------------------------------------------------------------------------
// Attention: one wave per batch row (lane covers d and d+64). 5 dots via
// shuffle reduce, softmax(4), weighted sum, leaky_relu. 2048 blocks x 256.
// ---------------------------------------------------------------------------
__global__ __launch_bounds__(256)
void att_kernel(const float* __restrict__ emb, const int* __restrict__ ids,
                const float* __restrict__ w_att, const float* __restrict__ agg,
                float* __restrict__ cur, const int l)
{
    const int wid  = threadIdx.x >> 6;
    const int lane = threadIdx.x & 63;
    const int b    = blockIdx.x * 4 + wid;

    const float* waH  = w_att + l * 2 * ND;
    const float* waT  = waH + ND;
    const float* crow = (l == 0) ? (emb + (size_t)ids[b] * ND) : (cur + (size_t)b * ND);
    const float* ab   = agg + ((size_t)(l * NT) * NB + b) * ND;   // + tt*NB*ND

    const float c1 = crow[lane], c2 = crow[lane + 64];
    const float h1 = waH[lane],  h2 = waH[lane + 64];
    const float t1 = waT[lane],  t2 = waT[lane + 64];
    float g1[3], g2[3];
    #pragma unroll
    for (int tt = 0; tt < 3; ++tt) {
        g1[tt] = ab[(size_t)tt * NB * ND + lane];
        g2[tt] = ab[(size_t)tt * NB * ND + lane + 64];
    }

    float dH = c1 * h1 + c2 * h2;
    float dc = c1 * t1 + c2 * t2;
    float d0 = g1[0] * t1 + g2[0] * t2;
    float d1 = g1[1] * t1 + g2[1] * t2;
    float d2 = g1[2] * t1 + g2[2] * t2;
    #pragma unroll
    for (int off = 32; off > 0; off >>= 1) {
        dH += __shfl_xor(dH, off);
        dc += __shfl_xor(dc, off);
        d0 += __shfl_xor(d0, off);
        d1 += __shfl_xor(d1, off);
        d2 += __shfl_xor(d2, off);
    }

    float s0 = dH + dc, s1 = dH + d0, s2 = dH + d1, s3 = dH + d2;
    float m  = fmaxf(fmaxf(s0, s1), fmaxf(s2, s3));
    float q0 = __expf(s0 - m), q1 = __expf(s1 - m), q2 = __expf(s2 - m), q3 = __expf(s3 - m);
    float inv = __fdividef(1.0f, q0 + q1 + q2 + q3);
    float w0 = q0 * inv, w1 = q1 * inv, w2 = q2 * inv, w3 = q3 * inv;

    float o1 = w0 * c1 + w1 * g1[0] + w2 * g1[1] + w3 * g1[2];
    float o2 = w0 * c2 + w1 * g2[0] + w2 * g2[1] + w3 * g2[2];
    o1 = (o1 > 0.f) ? o1 : 0.01f * o1;
    o2 = (o2 > 0.f) ? o2 : 0.01f * o2;

    float* orow = cur + (size_t)b * ND;
    orow[lane]      = o1;
    orow[lane + 64] = o2;
}

extern "C" void kernel_launch(void* const* d_in, const int* in_sizes, int n_in,
                              void* d_out, int out_size, void* d_ws, size_t ws_size,
                              hipStream_t stream)
{
    const float* emb  = (const float*)d_in[0];
    const float* Wih  = (const float*)d_in[1];
    const float* Whh  = (const float*)d_in[2];
    const float* bih  = (const float*)d_in[3];
    const float* bhh  = (const float*)d_in[4];
    const float* watt = (const float*)d_in[5];
    const int*   ids  = (const int*)d_in[6];
    const int*   nidx = (const int*)d_in[7];

    float* cur = (float*)d_out;            // [B][D] fp32, final output
    float* agg = (float*)d_ws;             // [L][T][B][D] fp32 = 25 MB

    rnn_kernel<<<dim3(NT * (NB / ROWS)), dim3(256), 0, stream>>>(emb, Wih, Whh, bih, bhh, nidx, agg);
    att_kernel<<<dim3(NB / 4), dim3(256), 0, stream>>>(emb, ids, watt, agg, cur, 0);
    att_kernel<<<dim3(NB / 4), dim3(256), 0, stream>>>(emb, ids, watt, agg, cur, 1);
}

// Round 13
// 78.768 us; speedup vs baseline: 1.5166x; 1.5166x over previous
//
#include <hip/hip_runtime.h>
#include <hip/hip_bf16.h>

#define NB   8192   // batch
#define NS   10     // neighbor seq len
#define NT   3      // node types
#define NN   65536  // table size
#define ND   128    // embed dim
#define NL   2      // layers
#define ROWS 32     // batch rows per block

typedef __attribute__((ext_vector_type(8))) short bf16x8;
typedef __attribute__((ext_vector_type(4))) float f32x4;

__device__ __forceinline__ unsigned int pk2(float lo, float hi) {
    unsigned int r;
    asm("v_cvt_pk_bf16_f32 %0, %1, %2" : "=v"(r) : "v"(lo), "v"(hi));
    return r;
}
// tanh(x) = 1 - 2/(exp2(2*log2e*x)+1)
__device__ __forceinline__ float tanh_f(float x) {
    float e, r;
    asm("v_exp_f32 %0, %1" : "=v"(e) : "v"(x * 2.88539004f));
    asm("v_rcp_f32 %0, %1" : "=v"(r) : "v"(e + 1.0f));
    return fmaf(-2.0f, r, 1.0f);
}
// Barrier with LDS-only drain: global (vmcnt) loads stay in flight across it.
__device__ __forceinline__ void bar_lgkm() {
    asm volatile("s_waitcnt lgkmcnt(0)\n\ts_barrier" ::: "memory");
}

// ---------------------------------------------------------------------------
// RNN kernel (r9 structure + register diet): grid = NT*256 blocks, 512 thr
// (8 waves = layer(2) x e-slice(4 of 32e)). Block owns (t, 32 rows), both
// layers; X staged once/step for all 8 waves. Register budget is the whole
// experiment: unified VGPR+AGPR total <= 128 doubles resident waves (r8 vs
// r9/r11/r12 evidence: per-wave-step latency ~4.4Kcy is constant; duration
// scales 1/waves_resident). Diet vs r9: rolling 1-reg idx prefetch (was
// idxs[10]), 8 addr regs with nt/parity as fold-in immediates (was 12).
// NO launch_bounds min-waves (r7/r10: cap below working set = spills).
// ---------------------------------------------------------------------------
__global__ __launch_bounds__(512)
void rnn_kernel(const float* __restrict__ emb, const float* __restrict__ Wih,
                const float* __restrict__ Whh, const float* __restrict__ bih,
                const float* __restrict__ bhh, const int* __restrict__ nidx,
                float* __restrict__ agg)
{
    // [X p0 | X p1 | H(l0) p0 | H(l0) p1 | H(l1) p0 | H(l1) p1], 8 KB each
    __shared__ __align__(16) char lds[6 * 8192];

    const int bid = blockIdx.x;                 // NT * (NB/ROWS)
    const int t   = bid / (NB / ROWS);
    const int b0  = (bid % (NB / ROWS)) * ROWS;

    const int tid  = threadIdx.x;
    const int wv   = tid >> 6;
    const int lay  = wv >> 2;        // layer 0/1
    const int lane = tid & 63;
    const int l16  = lane & 15;
    const int lg   = lane >> 4;
    const int e0   = (wv & 3) * 32;  // e-slice within layer
    const int rx   = l16 & 7;        // read-swizzle key (rows stride 16)

    char* xb = lds;
    char* hb = lds + 16384 + lay * 16384;

    // staging geometry: 16 threads per row, 8 floats (one 16B bf16 chunk) each
    const int srow  = tid >> 4;      // 0..31
    const int sq    = tid & 15;      // chunk index
    const int xaddr = srow * 256 + ((sq ^ (srow & 7)) << 4);

    // ---- rolling neighbor-index prefetch (1 live reg, not idxs[10]) ----
    const int* ip = nidx + ((size_t)t * NB + b0 + srow) * NS;
    int idx_nxt = ip[1];

    // ---- prefetch s=0 gather (lands while W-fragments are built) ----
    float4 P0, P1;
    {
        const float* src = emb + ((size_t)t * NN + ip[0]) * ND + sq * 8;
        P0 = *(const float4*)(src);
        P1 = *(const float4*)(src + 4);
    }

    const float* Wih_lt = Wih + (size_t)(lay * NT + t) * ND * ND;
    const float* Whh_lt = Whh + (size_t)(lay * NT + t) * ND * ND;
    const float* bih_lt = bih + (size_t)(lay * NT + t) * ND;
    const float* bhh_lt = bhh + (size_t)(lay * NT + t) * ND;

    // ---- A-fragments: rows e = e0 + mt*16 + l16, k-chunk kc (kc<4: Wih) ----
    bf16x8 Af[2][8];
    #pragma unroll
    for (int mt = 0; mt < 2; ++mt) {
        #pragma unroll
        for (int kc = 0; kc < 8; ++kc) {
            const float* Wsrc = (kc < 4) ? Wih_lt : Whh_lt;
            const float* srcp = Wsrc + (size_t)(e0 + mt * 16 + l16) * ND + (kc & 3) * 32 + lg * 8;
            float4 p0 = *(const float4*)(srcp);
            float4 p1 = *(const float4*)(srcp + 4);
            int4 a;
            a.x = (int)pk2(p0.x, p0.y);
            a.y = (int)pk2(p0.z, p0.w);
            a.z = (int)pk2(p1.x, p1.y);
            a.w = (int)pk2(p1.z, p1.w);
            Af[mt][kc] = *(bf16x8*)&a;
        }
    }

    // bias folded into MFMA C-init
    f32x4 biasv[2];
    #pragma unroll
    for (int mt = 0; mt < 2; ++mt) {
        int e = e0 + mt * 16 + lg * 4;
        float4 bi = *(const float4*)(bih_lt + e);
        float4 bh = *(const float4*)(bhh_lt + e);
        biasv[mt][0] = bi.x + bh.x;
        biasv[mt][1] = bi.y + bh.y;
        biasv[mt][2] = bi.z + bh.z;
        biasv[mt][3] = bi.w + bh.w;
    }

    // minimal precomputed LDS addressing (nt / parity folded as immediates)
    const int rowb = l16 * 256;                  // row base within 16-row tile
    int rdch[4];                                 // read chunk offsets, shared X/H
    #pragma unroll
    for (int c = 0; c < 4; ++c)
        rdch[c] = ((c * 4 + lg) ^ rx) << 4;
    int hwch[2];                                 // H-write chunk offs (+byte-in-chunk)
    #pragma unroll
    for (int mt = 0; mt < 2; ++mt)
        hwch[mt] = (((((e0 >> 3) + 2 * mt) + (lg >> 1)) ^ rx) << 4) + (lg & 1) * 8;

    f32x4 zero4; zero4[0] = 0.f; zero4[1] = 0.f; zero4[2] = 0.f; zero4[3] = 0.f;
    f32x4 Ag[2][2];
    #pragma unroll
    for (int nt = 0; nt < 2; ++nt) { Ag[nt][0] = zero4; Ag[nt][1] = zero4; }

    #pragma unroll
    for (int s = 0; s < NS; ++s) {
        const int par = (s & 1) * 8192;
        const int ppar = ((s + 1) & 1) * 8192;
        // ---- pack prefetched X_s -> swizzled LDS store (1x ds_write_b128) ----
        {
            int4 pk;
            pk.x = (int)pk2(P0.x, P0.y);
            pk.y = (int)pk2(P0.z, P0.w);
            pk.z = (int)pk2(P1.x, P1.y);
            pk.w = (int)pk2(P1.z, P1.w);
            *(int4*)(xb + xaddr + par) = pk;
        }
        // ---- issue next-step gather; stays in flight across the barrier ----
        if (s + 1 < NS) {
            const float* src = emb + ((size_t)t * NN + idx_nxt) * ND + sq * 8;
            P0 = *(const float4*)(src);
            P1 = *(const float4*)(src + 4);
            if (s + 2 < NS) idx_nxt = ip[s + 2];
        }
        bar_lgkm();   // X_s and H_{s-1} visible to all 8 waves; vmcnt in flight

        // ---- acc = bias + W2-slice x Z-rows (K=256: X then H of own layer) ----
        f32x4 acc[2][2];
        #pragma unroll
        for (int nt = 0; nt < 2; ++nt) { acc[nt][0] = biasv[0]; acc[nt][1] = biasv[1]; }

        #pragma unroll
        for (int nt = 0; nt < 2; ++nt)
            #pragma unroll
            for (int c = 0; c < 4; ++c) {
                bf16x8 bf = *(const bf16x8*)(xb + rowb + rdch[c] + nt * 4096 + par);
                acc[nt][0] = __builtin_amdgcn_mfma_f32_16x16x32_bf16(Af[0][c], bf, acc[nt][0], 0, 0, 0);
                acc[nt][1] = __builtin_amdgcn_mfma_f32_16x16x32_bf16(Af[1][c], bf, acc[nt][1], 0, 0, 0);
            }
        if (s > 0) {
            #pragma unroll
            for (int nt = 0; nt < 2; ++nt)
                #pragma unroll
                for (int c = 0; c < 4; ++c) {
                    bf16x8 bf = *(const bf16x8*)(hb + rowb + rdch[c] + nt * 4096 + ppar);
                    acc[nt][0] = __builtin_amdgcn_mfma_f32_16x16x32_bf16(Af[0][c + 4], bf, acc[nt][0], 0, 0, 0);
                    acc[nt][1] = __builtin_amdgcn_mfma_f32_16x16x32_bf16(Af[1][c + 4], bf, acc[nt][1], 0, 0, 0);
                }
        }

        // ---- tanh + agg accumulate + packed H writeback (other H buffer) ----
        #pragma unroll
        for (int nt = 0; nt < 2; ++nt)
            #pragma unroll
            for (int mt = 0; mt < 2; ++mt) {
                f32x4 h;
                #pragma unroll
                for (int i = 0; i < 4; ++i)
                    h[i] = tanh_f(acc[nt][mt][i]);
                Ag[nt][mt] += h;
                int2 pk;
                pk.x = (int)pk2(h[0], h[1]);
                pk.y = (int)pk2(h[2], h[3]);
                *(int2*)(hb + rowb + hwch[mt] + nt * 4096 + par) = pk;
            }
    }

    // agg[l][t][b][e]: lane writes float4 of 4 consecutive e at its row b
    float* aggp = agg + ((size_t)(lay * NT + t) * NB + b0) * ND;
    #pragma unroll
    for (int nt = 0; nt < 2; ++nt)
        #pragma unroll
        for (int mt = 0; mt < 2; ++mt) {
            f32x4 v = Ag[nt][mt] * 0.1f;
            *(f32x4*)(aggp + (size_t)(nt * 16 + l16) * ND + e0 + mt * 16 + lg * 4) = v;
        }
}

// ---------------------------------------------------------------------------
// Attention: one wave per batch row (lane covers d and d+64). 5 dots via
// shuffle reduce, softmax(4), weighted sum, leaky_relu. 2048 blocks x 256.
// ---------------------------------------------------------------------------
__global__ __launch_bounds__(256)
void att_kernel(const float* __restrict__ emb, const int* __restrict__ ids,
                const float* __restrict__ w_att, const float* __restrict__ agg,
                float* __restrict__ cur, const int l)
{
    const int wid  = threadIdx.x >> 6;
    const int lane = threadIdx.x & 63;
    const int b    = blockIdx.x * 4 + wid;

    const float* waH  = w_att + l * 2 * ND;
    const float* waT  = waH + ND;
    const float* crow = (l == 0) ? (emb + (size_t)ids[b] * ND) : (cur + (size_t)b * ND);
    const float* ab   = agg + ((size_t)(l * NT) * NB + b) * ND;   // + tt*NB*ND

    const float c1 = crow[lane], c2 = crow[lane + 64];
    const float h1 = waH[lane],  h2 = waH[lane + 64];
    const float t1 = waT[lane],  t2 = waT[lane + 64];
    float g1[3], g2[3];
    #pragma unroll
    for (int tt = 0; tt < 3; ++tt) {
        g1[tt] = ab[(size_t)tt * NB * ND + lane];
        g2[tt] = ab[(size_t)tt * NB * ND + lane + 64];
    }

    float dH = c1 * h1 + c2 * h2;
    float dc = c1 * t1 + c2 * t2;
    float d0 = g1[0] * t1 + g2[0] * t2;
    float d1 = g1[1] * t1 + g2[1] * t2;
    float d2 = g1[2] * t1 + g2[2] * t2;
    #pragma unroll
    for (int off = 32; off > 0; off >>= 1) {
        dH += __shfl_xor(dH, off);
        dc += __shfl_xor(dc, off);
        d0 += __shfl_xor(d0, off);
        d1 += __shfl_xor(d1, off);
        d2 += __shfl_xor(d2, off);
    }

    float s0 = dH + dc, s1 = dH + d0, s2 = dH + d1, s3 = dH + d2;
    float m  = fmaxf(fmaxf(s0, s1), fmaxf(s2, s3));
    float q0 = __expf(s0 - m), q1 = __expf(s1 - m), q2 = __expf(s2 - m), q3 = __expf(s3 - m);
    float inv = __fdividef(1.0f, q0 + q1 + q2 + q3);
    float w0 = q0 * inv, w1 = q1 * inv, w2 = q2 * inv, w3 = q3 * inv;

    float o1 = w0 * c1 + w1 * g1[0] + w2 * g1[1] + w3 * g1[2];
    float o2 = w0 * c2 + w1 * g2[0] + w2 * g2[1] + w3 * g2[2];
    o1 = (o1 > 0.f) ? o1 : 0.01f * o1;
    o2 = (o2 > 0.f) ? o2 : 0.01f * o2;

    float* orow = cur + (size_t)b * ND;
    orow[lane]      = o1;
    orow[lane + 64] = o2;
}

extern "C" void kernel_launch(void* const* d_in, const int* in_sizes, int n_in,
                              void* d_out, int out_size, void* d_ws, size_t ws_size,
                              hipStream_t stream)
{
    const float* emb  = (const float*)d_in[0];
    const float* Wih  = (const float*)d_in[1];
    const float* Whh  = (const float*)d_in[2];
    const float* bih  = (const float*)d_in[3];
    const float* bhh  = (const float*)d_in[4];
    const float* watt = (const float*)d_in[5];
    const int*   ids  = (const int*)d_in[6];
    const int*   nidx = (const int*)d_in[7];

    float* cur = (float*)d_out;            // [B][D] fp32, final output
    float* agg = (float*)d_ws;             // [L][T][B][D] fp32 = 25 MB

    rnn_kernel<<<dim3(NT * (NB / ROWS)), dim3(512), 0, stream>>>(emb, Wih, Whh, bih, bhh, nidx, agg);
    att_kernel<<<dim3(NB / 4), dim3(256), 0, stream>>>(emb, ids, watt, agg, cur, 0);
    att_kernel<<<dim3(NB / 4), dim3(256), 0, stream>>>(emb, ids, watt, agg, cur, 1);
}